// Round 9
// baseline (89.492 us; speedup 1.0000x reference)
//
#include <hip/hip_runtime.h>

typedef unsigned short u16;
using bf16x8 = __attribute__((ext_vector_type(8))) __bf16;
using f32x4  = __attribute__((ext_vector_type(4))) float;
using f32x16 = __attribute__((ext_vector_type(16))) float;
using u16x8  = __attribute__((ext_vector_type(8))) u16;
using u32x2  = __attribute__((ext_vector_type(2))) unsigned;

constexpr float QSC = 0.180336880111112f;  // 0.125 * log2(e): softmax in exp2 domain

#define TID ((int)threadIdx.x)

__device__ __forceinline__ float fexp2(float x) {
#if __has_builtin(__builtin_amdgcn_exp2f)
  return __builtin_amdgcn_exp2f(x);
#else
  return exp2f(x);
#endif
}
__device__ __forceinline__ u16 f2bf(float f) {
  __bf16 h = (__bf16)f;
  return __builtin_bit_cast(u16, h);
}
// packed f32x2 -> bf16x2 (RNE), single instruction (T12 recipe; src0 -> lo16)
__device__ __forceinline__ unsigned cvtpk(float a, float b) {
  unsigned r;
  asm("v_cvt_pk_bf16_f32 %0, %1, %2" : "=v"(r) : "v"(a), "v"(b));
  return r;
}
// cross-half (lane i <-> lane i^32) reduce via permlane32_swap.
// Used ONLY where the result is invariant to the swap direction.
__device__ __forceinline__ u32x2 plswap(unsigned d, unsigned s) {
#if __has_builtin(__builtin_amdgcn_permlane32_swap)
  return __builtin_amdgcn_permlane32_swap(d, s, false, false);
#else
  unsigned dx = (unsigned)__shfl_xor((int)d, 32);
  unsigned sx = (unsigned)__shfl_xor((int)s, 32);
  int hh = ((int)threadIdx.x >> 5) & 1;
  u32x2 r;
  r[0] = hh ? d : sx;
  r[1] = hh ? dx : s;
  return r;
#endif
}
__device__ __forceinline__ float xhalf_max(float x) {
  unsigned u = __builtin_bit_cast(unsigned, x);
  u32x2 r = plswap(u, u);
  return fmaxf(__builtin_bit_cast(float, r[0]), __builtin_bit_cast(float, r[1]));
}
__device__ __forceinline__ float xhalf_add(float x) {
  unsigned u = __builtin_bit_cast(unsigned, x);
  u32x2 r = plswap(u, u);
  return __builtin_bit_cast(float, r[0]) + __builtin_bit_cast(float, r[1]);
}
__device__ __forceinline__ bf16x8 ldfrag(const u16* p) {
  return __builtin_bit_cast(bf16x8, *(const u16x8*)p);
}
// XOR swizzle of 16B chunks within a 128B row (involution per row);
// note swz(row+64,ch) == swz(row,ch), so 64-row sub-tiles share the layout.
__device__ __forceinline__ int swz(int row, int ch) {
  return ch ^ (row & 7) ^ ((row >> 3) & 7);
}
// async global->LDS, 16B per lane; LDS dest linear (wave-uniform base + lane*16)
__device__ __forceinline__ void gload16(const u16* g, u16* l) {
  __builtin_amdgcn_global_load_lds(
      (__attribute__((address_space(1))) void*)g,
      (__attribute__((address_space(3))) void*)l, 16, 0, 0);
}
__device__ __forceinline__ f32x4 mfma16(bf16x8 a, bf16x8 b, f32x4 c) {
  return __builtin_amdgcn_mfma_f32_16x16x32_bf16(a, b, c, 0, 0, 0);
}
__device__ __forceinline__ f32x16 mfma32(bf16x8 a, bf16x8 b, f32x16 c) {
  return __builtin_amdgcn_mfma_f32_32x32x16_bf16(a, b, c, 0, 0, 0);
}

// ---------------- fused: weight fp32->bf16 (blocks 0..1023) + GN stats (1024..1279) ----
__global__ __launch_bounds__(256) void prep_stats(
    const float* __restrict__ wq, const float* __restrict__ wp,
    u16* __restrict__ wqb, u16* __restrict__ wpb,
    const float* __restrict__ x, float* __restrict__ stats) {
  __shared__ float sm[4], ssm[4];
  int bid = blockIdx.x;
  if (bid < 1024) {
    int i = bid * 256 + TID;
    if (i < 196608) {
      float4 v = ((const float4*)wq)[i];
      u16* o = wqb + i * 4;
      o[0] = f2bf(v.x); o[1] = f2bf(v.y); o[2] = f2bf(v.z); o[3] = f2bf(v.w);
    } else {
      int j = i - 196608;
      float4 v = ((const float4*)wp)[j];
      u16* o = wpb + j * 4;
      o[0] = f2bf(v.x); o[1] = f2bf(v.y); o[2] = f2bf(v.z); o[3] = f2bf(v.w);
    }
    return;
  }
  int blk = bid - 1024;
  size_t base = ((size_t)blk) << 14;
  const float4* xp = (const float4*)(x + base);
  float s = 0.f, ss = 0.f;
#pragma unroll
  for (int i = 0; i < 16; ++i) {
    float4 v = xp[TID + i * 256];
    s += v.x + v.y + v.z + v.w;
    ss += v.x * v.x + v.y * v.y + v.z * v.z + v.w * v.w;
  }
#pragma unroll
  for (int off = 32; off; off >>= 1) {
    s += __shfl_down(s, off);
    ss += __shfl_down(ss, off);
  }
  if ((TID & 63) == 0) { sm[TID >> 6] = s; ssm[TID >> 6] = ss; }
  __syncthreads();
  if (TID == 0) {
    float tot = sm[0] + sm[1] + sm[2] + sm[3];
    float tots = ssm[0] + ssm[1] + ssm[2] + ssm[3];
    float mean = tot * (1.f / 16384.f);
    float var = tots * (1.f / 16384.f) - mean * mean;
    stats[blk * 2] = mean;
    stats[blk * 2 + 1] = rsqrtf(var + 1e-5f);
  }
}

// ---------------- GroupNorm apply: -> xnT[b][l][c] bf16 ----------------
__global__ __launch_bounds__(256) void gn_apply(
    const float* __restrict__ x, const float* __restrict__ gamma,
    const float* __restrict__ beta, const float* __restrict__ stats,
    u16* __restrict__ xnT) {
  __shared__ u16 xt[32 * 520];
  int l0 = blockIdx.x * 32, b = blockIdx.y;
  int li = TID & 31, cb = TID >> 5;
#pragma unroll 4
  for (int it = 0; it < 64; ++it) {
    int c = it * 8 + cb;
    int g = c >> 4;
    float mean = stats[(b * 32 + g) * 2];
    float rstd = stats[(b * 32 + g) * 2 + 1];
    float ga = gamma[c] * rstd;
    float be = beta[c] - mean * ga;
    float v = x[((size_t)b * 512 + c) * 1024 + l0 + li];
    xt[li * 520 + c] = f2bf(v * ga + be);
  }
  __syncthreads();
  int li2 = TID >> 3, u0 = TID & 7;
#pragma unroll
  for (int it = 0; it < 8; ++it) {
    int unit = u0 + it * 8;
    u16x8 v = *(const u16x8*)&xt[li2 * 520 + unit * 8];
    *(u16x8*)&xnT[((size_t)b * 1024 + l0 + li2) * 512 + unit * 8] = v;
  }
}

// ---------------- unified QKV GEMM (transposed product D[l][o]) ----------------
__global__ __launch_bounds__(256) void qkv_gemm(
    const u16* __restrict__ A, const u16* __restrict__ Bt,
    const float* __restrict__ bias,
    u16* __restrict__ qT, u16* __restrict__ kT, u16* __restrict__ vbuf) {
  __shared__ u16 Al[8192], Bl[8192];
  int lin = blockIdx.x;            // 768 = 8 XCD chunks x 96 (12 m x 8 n)
  int b = lin & 7;                 // one batch per XCD
  int rem = lin >> 3;
  int mi = rem % 12, ni = rem / 12;
  int m0 = mi * 128, n0 = ni * 128;
  int lane = TID & 63, w = TID >> 6;
  int mw = (w >> 1) * 64, nw = (w & 1) * 64;
  const u16* Bb = Bt + (size_t)b * 1024 * 512;
  f32x4 acc[4][4] = {};
  for (int k0 = 0; k0 < 512; k0 += 64) {
#pragma unroll
    for (int u = 0; u < 4; ++u) {
      int unit = u * 256 + TID, row = unit >> 3, ch = unit & 7;
      gload16(&A[(size_t)(m0 + row) * 512 + k0 + swz(row, ch) * 8], &Al[unit * 8]);
      gload16(&Bb[(size_t)(n0 + row) * 512 + k0 + swz(row, ch) * 8], &Bl[unit * 8]);
    }
    __syncthreads();
    bf16x8 xf[4][2];
#pragma unroll
    for (int xi = 0; xi < 4; ++xi)
#pragma unroll
      for (int kf = 0; kf < 2; ++kf) {
        int row = nw + xi * 16 + (lane & 15);
        int lc = kf * 4 + (lane >> 4);
        xf[xi][kf] = ldfrag(&Bl[row * 64 + swz(row, lc) * 8]);
      }
#pragma unroll
    for (int yi = 0; yi < 4; ++yi) {
      int row = mw + yi * 16 + (lane & 15);
      int lc = lane >> 4;
      bf16x8 y0 = ldfrag(&Al[row * 64 + swz(row, lc) * 8]);
      bf16x8 y1 = ldfrag(&Al[row * 64 + swz(row, lc + 4) * 8]);
#pragma unroll
      for (int xi = 0; xi < 4; ++xi) {
        acc[xi][yi] = mfma16(xf[xi][0], y0, acc[xi][yi]);
        acc[xi][yi] = mfma16(xf[xi][1], y1, acc[xi][yi]);
      }
    }
    __syncthreads();
  }
  int sel = m0 >> 9;  // 0=Q 1=K 2=V
  int ho = w >> 1;
  u16* RP = ho ? Bl : Al;
  if (sel < 2) {
#pragma unroll
    for (int xi = 0; xi < 4; ++xi)
#pragma unroll
      for (int yi = 0; yi < 4; ++yi)
#pragma unroll
        for (int r = 0; r < 4; ++r) {
          int lloc = nw + xi * 16 + (lane >> 4) * 4 + r;
          int oc = yi * 16 + (lane & 15);
          float v = acc[xi][yi][r] + bias[m0 + ho * 64 + oc];
          if (sel == 0) v *= QSC;
          RP[lloc * 64 + swz(lloc, oc >> 3) * 8 + (oc & 7)] = f2bf(v);
        }
    __syncthreads();
    u16* dst = sel ? kT : qT;
    int h0 = (m0 & 511) >> 6;
#pragma unroll
    for (int uu = 0; uu < 4; ++uu) {
      int unit = uu * 256 + TID, row = unit >> 3, ch = unit & 7;
      u16x8 v0 = *(const u16x8*)&Al[row * 64 + swz(row, ch) * 8];
      u16x8 v1 = *(const u16x8*)&Bl[row * 64 + swz(row, ch) * 8];
      *(u16x8*)&dst[((size_t)(b * 8 + h0) * 1024 + n0 + row) * 64 + ch * 8] = v0;
      *(u16x8*)&dst[((size_t)(b * 8 + h0 + 1) * 1024 + n0 + row) * 64 + ch * 8] = v1;
    }
  } else {
#pragma unroll
    for (int xi = 0; xi < 4; ++xi)
#pragma unroll
      for (int yi = 0; yi < 4; ++yi)
#pragma unroll
        for (int r = 0; r < 4; ++r) {
          int lloc = nw + xi * 16 + (lane >> 4) * 4 + r;
          int oc = yi * 16 + (lane & 15);
          float v = acc[xi][yi][r] + bias[m0 + ho * 64 + oc];
          RP[oc * 128 + swz(oc, lloc >> 3) * 8 + (lloc & 7)] = f2bf(v);
        }
    __syncthreads();
    int h0 = (m0 - 1024) >> 6;
#pragma unroll
    for (int uu = 0; uu < 4; ++uu) {
      int unit = uu * 256 + TID, ro = unit >> 4, ch = unit & 15;
      u16x8 v0 = *(const u16x8*)&Al[ro * 128 + swz(ro, ch) * 8];
      u16x8 v1 = *(const u16x8*)&Bl[ro * 128 + swz(ro, ch) * 8];
      *(u16x8*)&vbuf[((size_t)(b * 8 + h0) * 64 + ro) * 1024 + n0 + ch * 8] = v0;
      *(u16x8*)&vbuf[((size_t)(b * 8 + h0 + 1) * 64 + ro) * 1024 + n0 + ch * 8] = v1;
    }
  }
}

// ---------------- MFMA flash attention, 32x32, swapped operands ----------------
// KVBLK=128: stage 128 s of K/V per iter (dbuf 2x32KB), ONE barrier per 128 s,
// two 64-s sub-tiles per iter (identical verified body; swz(row+64)==swz(row)).
__global__ __launch_bounds__(256) void attn_mfma(const u16* __restrict__ qT,
                                                 const u16* __restrict__ kT,
                                                 const u16* __restrict__ vb,
                                                 u16* __restrict__ aT) {
  __shared__ u16 smem[32768];  // 2 x (K[128][64] | V[2][64][64]); repack reuses buf0
  int lin = blockIdx.x;
  int rem = lin >> 3;
  int bh = (lin & 7) * 8 + (rem >> 3);
  int t0 = (rem & 7) * 128;
  int b = bh >> 3, hd = bh & 7;
  int lane = TID & 63, w = TID >> 6;
  int h = lane >> 5, ln = lane & 31;
  int t = t0 + w * 32 + ln;
  const u16* qp = qT + ((size_t)bh * 1024 + t) * 64;
  const u16* kbase = kT + (size_t)bh * 1024 * 64;
  const u16* vbase = vb + (size_t)bh * 64 * 1024;
  bf16x8 qf[4];
#pragma unroll
  for (int kc = 0; kc < 4; ++kc) qf[kc] = ldfrag(qp + kc * 16 + h * 8);
  float m_r = -1e30f, l_r = 0.f;
  f32x16 oacc[2] = {};

  // staging: K unit -> row=unit>>3 (0..127), ch=unit&7 ; dest Kb[unit*8] (linear)
  //          V unit -> half=unit>>9, c=(unit>>3)&63, ch=unit&7 ; dest Vb[unit*8]
  {
    u16* Kb = smem;
    u16* Vb = smem + 8192;
#pragma unroll
    for (int it = 0; it < 4; ++it) {
      int unit = it * 256 + TID, row = unit >> 3, ch = unit & 7;
      gload16(&kbase[(size_t)row * 64 + swz(row, ch) * 8], &Kb[unit * 8]);
    }
#pragma unroll
    for (int it = 0; it < 4; ++it) {
      int unit = it * 256 + TID;
      int half = unit >> 9, c = (unit >> 3) & 63, ch = unit & 7;
      gload16(&vbase[(size_t)c * 1024 + half * 64 + swz(c, ch) * 8], &Vb[unit * 8]);
    }
  }
  __syncthreads();
  for (int tile = 0; tile < 8; ++tile) {
    const u16* Kb = smem + (tile & 1) * 16384;
    const u16* Vb = Kb + 8192;
    if (tile < 7) {  // issue next 128-s tile into buf^1
      int sn = (tile + 1) * 128;
      u16* Kn = smem + ((tile + 1) & 1) * 16384;
      u16* Vn = Kn + 8192;
#pragma unroll
      for (int it = 0; it < 4; ++it) {
        int unit = it * 256 + TID, row = unit >> 3, ch = unit & 7;
        gload16(&kbase[(size_t)(sn + row) * 64 + swz(row, ch) * 8], &Kn[unit * 8]);
      }
#pragma unroll
      for (int it = 0; it < 4; ++it) {
        int unit = it * 256 + TID;
        int half = unit >> 9, c = (unit >> 3) & 63, ch = unit & 7;
        gload16(&vbase[(size_t)c * 1024 + sn + half * 64 + swz(c, ch) * 8],
                &Vn[unit * 8]);
      }
    }
#pragma unroll
    for (int sub = 0; sub < 2; ++sub) {
      const u16* Ks = Kb + sub * 4096;
      const u16* Vs = Vb + sub * 4096;
      // S^T[s][t] = sum_c K[s][c] * Q[t][c]  (log2 units; Q pre-scaled by QSC)
      f32x16 sacc[2] = {};
      __builtin_amdgcn_s_setprio(1);
#pragma unroll
      for (int sb = 0; sb < 2; ++sb) {
        int srow = sb * 32 + ln;
#pragma unroll
        for (int kc = 0; kc < 4; ++kc) {
          bf16x8 kf = ldfrag(&Ks[srow * 64 + swz(srow, kc * 2 + h) * 8]);
          sacc[sb] = mfma32(kf, qf[kc], sacc[sb]);
        }
      }
      __builtin_amdgcn_s_setprio(0);
      // online softmax; lane owns row t, 32 of 64 s-values (partner = lane^32)
      float mp[4];
#pragma unroll
      for (int q = 0; q < 4; ++q) {
        mp[q] = fmaxf(fmaxf(sacc[0][q * 4], sacc[0][q * 4 + 1]),
                      fmaxf(sacc[0][q * 4 + 2], sacc[0][q * 4 + 3]));
        mp[q] = fmaxf(mp[q], fmaxf(fmaxf(sacc[1][q * 4], sacc[1][q * 4 + 1]),
                                   fmaxf(sacc[1][q * 4 + 2], sacc[1][q * 4 + 3])));
      }
      float mx = xhalf_max(fmaxf(fmaxf(mp[0], mp[1]), fmaxf(mp[2], mp[3])));
      bool noresc = (__all(mx <= m_r + 8.f) != 0);
      if (!noresc) {
        float mn = fmaxf(m_r, mx);
        float al = fexp2(m_r - mn);
        m_r = mn;
        l_r *= al;
#pragma unroll
        for (int ca = 0; ca < 2; ++ca)
#pragma unroll
          for (int i = 0; i < 16; ++i) oacc[ca][i] *= al;
      }
      float rp[4] = {0.f, 0.f, 0.f, 0.f};
#pragma unroll
      for (int sb = 0; sb < 2; ++sb)
#pragma unroll
        for (int i = 0; i < 16; ++i) {
          float pv = fexp2(sacc[sb][i] - m_r);
          sacc[sb][i] = pv;
          rp[i & 3] += pv;
        }
      l_r += xhalf_add((rp[0] + rp[1]) + (rp[2] + rp[3]));
      // pack P pairs
      unsigned W[2][4][2];
#pragma unroll
      for (int sb = 0; sb < 2; ++sb)
#pragma unroll
        for (int p4 = 0; p4 < 4; ++p4)
#pragma unroll
          for (int e = 0; e < 2; ++e)
            W[sb][p4][e] =
                cvtpk(sacc[sb][p4 * 4 + 2 * e], sacc[sb][p4 * 4 + 2 * e + 1]);
      // per 16-k step m: exchange with lane^32, assemble B-frag, PV
#pragma unroll
      for (int m = 0; m < 4; ++m) {
        int sb = m >> 1, q = (m & 1) * 2;
        unsigned a0 = W[sb][q][0], a1 = W[sb][q][1];
        unsigned b0 = W[sb][q + 1][0], b1 = W[sb][q + 1][1];
        unsigned s0w = h ? a0 : b0;
        unsigned s1w = h ? a1 : b1;
        unsigned x0 = (unsigned)__shfl_xor((int)s0w, 32);
        unsigned x1 = (unsigned)__shfl_xor((int)s1w, 32);
        unsigned w0 = h ? x0 : a0;
        unsigned w1 = h ? x1 : a1;
        unsigned w2 = h ? b0 : x0;
        unsigned w3 = h ? b1 : x1;
        uint4 pw = make_uint4(w0, w1, w2, w3);
        bf16x8 pf = __builtin_bit_cast(bf16x8, pw);
        __builtin_amdgcn_s_setprio(1);
#pragma unroll
        for (int ca = 0; ca < 2; ++ca) {
          int crow = ca * 32 + ln;
          bf16x8 vf = ldfrag(&Vs[crow * 64 + swz(crow, m * 2 + h) * 8]);
          oacc[ca] = mfma32(vf, pf, oacc[ca]);  // O^T[c][t]
        }
        __builtin_amdgcn_s_setprio(0);
      }
    }
    __syncthreads();
  }
  // O^T -> LDS [t][c] (swizzled) -> coalesced aT[b][t][hd*64+c]
  float rl = 1.f / l_r;
  int tloc = w * 32 + ln;
#pragma unroll
  for (int ca = 0; ca < 2; ++ca)
#pragma unroll
    for (int p4 = 0; p4 < 4; ++p4)
#pragma unroll
      for (int e = 0; e < 2; ++e) {
        int r = p4 * 4 + e * 2;
        int c = ca * 32 + 8 * p4 + 4 * h + 2 * e;
        unsigned pk = cvtpk(oacc[ca][r] * rl, oacc[ca][r + 1] * rl);
        *(unsigned*)&smem[tloc * 64 + swz(tloc, c >> 3) * 8 + (c & 7)] = pk;
      }
  __syncthreads();
#pragma unroll
  for (int u = 0; u < 4; ++u) {
    int unit = u * 256 + TID;
    int row = unit >> 3, ch = unit & 7;
    u16x8 v = *(const u16x8*)&smem[row * 64 + swz(row, ch) * 8];
    *(u16x8*)&aT[((size_t)b * 1024 + t0 + row) * 512 + hd * 64 + ch * 8] = v;
  }
}

// ---------------- proj GEMM: 128m x 64n tiles, 512 blocks (2/CU) ----------------
__global__ __launch_bounds__(256) void proj_gemm(
    const u16* __restrict__ A, const u16* __restrict__ Bt,
    const float* __restrict__ bias, const float* __restrict__ resid,
    float* __restrict__ of) {
  __shared__ u16 Al[8192], Bl[4096];
  int lin = blockIdx.x;           // 512 = 8 XCD chunks x 64 (4 m x 16 n)
  int b = lin & 7;
  int rem = lin >> 3;
  int mi = rem & 3, ni4 = rem >> 2;  // ni4 0..15
  int m0 = mi * 128, n0 = ni4 * 64;
  int lane = TID & 63, w = TID >> 6;
  int mw2 = w * 32;  // wave owns 32 m-rows x 64 n
  const u16* Bb = Bt + (size_t)b * 1024 * 512;
  f32x4 acc[2][4] = {};
  for (int k0 = 0; k0 < 512; k0 += 64) {
#pragma unroll
    for (int u = 0; u < 4; ++u) {
      int unit = u * 256 + TID, row = unit >> 3, ch = unit & 7;
      gload16(&A[(size_t)(m0 + row) * 512 + k0 + swz(row, ch) * 8], &Al[unit * 8]);
    }
#pragma unroll
    for (int u = 0; u < 2; ++u) {
      int unit = u * 256 + TID, row = unit >> 3, ch = unit & 7;
      gload16(&Bb[(size_t)(n0 + row) * 512 + k0 + swz(row, ch) * 8], &Bl[unit * 8]);
    }
    __syncthreads();
    bf16x8 xf[2][2];
#pragma unroll
    for (int xi = 0; xi < 2; ++xi)
#pragma unroll
      for (int kf = 0; kf < 2; ++kf) {
        int row = mw2 + xi * 16 + (lane & 15);
        int lc = kf * 4 + (lane >> 4);
        xf[xi][kf] = ldfrag(&Al[row * 64 + swz(row, lc) * 8]);
      }
#pragma unroll
    for (int yi = 0; yi < 4; ++yi) {
      int row = yi * 16 + (lane & 15);
      int lc = lane >> 4;
      bf16x8 y0 = ldfrag(&Bl[row * 64 + swz(row, lc) * 8]);
      bf16x8 y1 = ldfrag(&Bl[row * 64 + swz(row, lc + 4) * 8]);
#pragma unroll
      for (int xi = 0; xi < 2; ++xi) {
        acc[xi][yi] = mfma16(xf[xi][0], y0, acc[xi][yi]);
        acc[xi][yi] = mfma16(xf[xi][1], y1, acc[xi][yi]);
      }
    }
    __syncthreads();
  }
#pragma unroll
  for (int xi = 0; xi < 2; ++xi)
#pragma unroll
    for (int yi = 0; yi < 4; ++yi)
#pragma unroll
      for (int r = 0; r < 4; ++r) {
        int o = m0 + mw2 + xi * 16 + (lane >> 4) * 4 + r;
        int l = n0 + yi * 16 + (lane & 15);
        size_t idx = ((size_t)b * 512 + o) * 1024 + l;
        of[idx] = acc[xi][yi][r] + bias[o] + resid[idx];
      }
}

extern "C" void kernel_launch(void* const* d_in, const int* in_sizes, int n_in,
                              void* d_out, int out_size, void* d_ws, size_t ws_size,
                              hipStream_t stream) {
  const float* x = (const float*)d_in[0];
  const float* gamma = (const float*)d_in[1];
  const float* beta = (const float*)d_in[2];
  const float* w_qkv = (const float*)d_in[3];
  const float* b_qkv = (const float*)d_in[4];
  const float* w_proj = (const float*)d_in[5];
  const float* b_proj = (const float*)d_in[6];
  float* out = (float*)d_out;

  u16* qT = (u16*)d_ws;                    // 64bh*1024*64 = 4194304 u16 (8MB)
  u16* kT = qT + 4194304;                  // 8MB
  u16* vbuf = kT + 4194304;                // 8MB
  u16* aTb = vbuf + 4194304;               // 8MB
  u16* wqb = aTb + 4194304;                // 1.5MB
  u16* wpb = wqb + 786432;                 // 0.5MB
  float* stats = (float*)(wpb + 262144);   // 512 floats
  u16* xnT = (u16*)d_out;                  // 8MB scratch in d_out (overwritten by proj)

  prep_stats<<<dim3(1280), dim3(256), 0, stream>>>(w_qkv, w_proj, wqb, wpb, x, stats);
  gn_apply<<<dim3(32, 8), dim3(256), 0, stream>>>(x, gamma, beta, stats, xnT);
  qkv_gemm<<<dim3(768), dim3(256), 0, stream>>>(wqb, xnT, b_qkv, qT, kT, vbuf);
  attn_mfma<<<dim3(512), dim3(256), 0, stream>>>(qT, kT, vbuf, aTb);
  proj_gemm<<<dim3(512), dim3(256), 0, stream>>>(wpb, aTb, b_proj, x, out);
}

// Round 10
// 86.313 us; speedup vs baseline: 1.0368x; 1.0368x over previous
//
#include <hip/hip_runtime.h>

typedef unsigned short u16;
using bf16x8 = __attribute__((ext_vector_type(8))) __bf16;
using f32x4  = __attribute__((ext_vector_type(4))) float;
using f32x16 = __attribute__((ext_vector_type(16))) float;
using u16x8  = __attribute__((ext_vector_type(8))) u16;
using u32x2  = __attribute__((ext_vector_type(2))) unsigned;

constexpr float QSC = 0.180336880111112f;  // 0.125 * log2(e): softmax in exp2 domain

#define TID ((int)threadIdx.x)

__device__ __forceinline__ float fexp2(float x) {
#if __has_builtin(__builtin_amdgcn_exp2f)
  return __builtin_amdgcn_exp2f(x);
#else
  return exp2f(x);
#endif
}
__device__ __forceinline__ u16 f2bf(float f) {
  __bf16 h = (__bf16)f;
  return __builtin_bit_cast(u16, h);
}
// packed f32x2 -> bf16x2 (RNE), single instruction (T12 recipe; src0 -> lo16)
__device__ __forceinline__ unsigned cvtpk(float a, float b) {
  unsigned r;
  asm("v_cvt_pk_bf16_f32 %0, %1, %2" : "=v"(r) : "v"(a), "v"(b));
  return r;
}
// cross-half (lane i <-> lane i^32) reduce via permlane32_swap.
// Used ONLY where the result is invariant to the swap direction.
__device__ __forceinline__ u32x2 plswap(unsigned d, unsigned s) {
#if __has_builtin(__builtin_amdgcn_permlane32_swap)
  return __builtin_amdgcn_permlane32_swap(d, s, false, false);
#else
  unsigned dx = (unsigned)__shfl_xor((int)d, 32);
  unsigned sx = (unsigned)__shfl_xor((int)s, 32);
  int hh = ((int)threadIdx.x >> 5) & 1;
  u32x2 r;
  r[0] = hh ? d : sx;
  r[1] = hh ? dx : s;
  return r;
#endif
}
__device__ __forceinline__ float xhalf_max(float x) {
  unsigned u = __builtin_bit_cast(unsigned, x);
  u32x2 r = plswap(u, u);
  return fmaxf(__builtin_bit_cast(float, r[0]), __builtin_bit_cast(float, r[1]));
}
__device__ __forceinline__ float xhalf_add(float x) {
  unsigned u = __builtin_bit_cast(unsigned, x);
  u32x2 r = plswap(u, u);
  return __builtin_bit_cast(float, r[0]) + __builtin_bit_cast(float, r[1]);
}
__device__ __forceinline__ bf16x8 ldfrag(const u16* p) {
  return __builtin_bit_cast(bf16x8, *(const u16x8*)p);
}
// XOR swizzle of 16B chunks within a 128B row (involution per row)
__device__ __forceinline__ int swz(int row, int ch) {
  return ch ^ (row & 7) ^ ((row >> 3) & 7);
}
// async global->LDS, 16B per lane; LDS dest linear (wave-uniform base + lane*16)
__device__ __forceinline__ void gload16(const u16* g, u16* l) {
  __builtin_amdgcn_global_load_lds(
      (__attribute__((address_space(1))) void*)g,
      (__attribute__((address_space(3))) void*)l, 16, 0, 0);
}
__device__ __forceinline__ f32x4 mfma16(bf16x8 a, bf16x8 b, f32x4 c) {
  return __builtin_amdgcn_mfma_f32_16x16x32_bf16(a, b, c, 0, 0, 0);
}
__device__ __forceinline__ f32x16 mfma32(bf16x8 a, bf16x8 b, f32x16 c) {
  return __builtin_amdgcn_mfma_f32_32x32x16_bf16(a, b, c, 0, 0, 0);
}

// ---------------- fused: weight fp32->bf16 (blocks 0..1023) + GN stats (1024..1279) ----
__global__ __launch_bounds__(256) void prep_stats(
    const float* __restrict__ wq, const float* __restrict__ wp,
    u16* __restrict__ wqb, u16* __restrict__ wpb,
    const float* __restrict__ x, float* __restrict__ stats) {
  __shared__ float sm[4], ssm[4];
  int bid = blockIdx.x;
  if (bid < 1024) {
    int i = bid * 256 + TID;
    if (i < 196608) {
      float4 v = ((const float4*)wq)[i];
      u16* o = wqb + i * 4;
      o[0] = f2bf(v.x); o[1] = f2bf(v.y); o[2] = f2bf(v.z); o[3] = f2bf(v.w);
    } else {
      int j = i - 196608;
      float4 v = ((const float4*)wp)[j];
      u16* o = wpb + j * 4;
      o[0] = f2bf(v.x); o[1] = f2bf(v.y); o[2] = f2bf(v.z); o[3] = f2bf(v.w);
    }
    return;
  }
  int blk = bid - 1024;
  size_t base = ((size_t)blk) << 14;
  const float4* xp = (const float4*)(x + base);
  float s = 0.f, ss = 0.f;
#pragma unroll
  for (int i = 0; i < 16; ++i) {
    float4 v = xp[TID + i * 256];
    s += v.x + v.y + v.z + v.w;
    ss += v.x * v.x + v.y * v.y + v.z * v.z + v.w * v.w;
  }
#pragma unroll
  for (int off = 32; off; off >>= 1) {
    s += __shfl_down(s, off);
    ss += __shfl_down(ss, off);
  }
  if ((TID & 63) == 0) { sm[TID >> 6] = s; ssm[TID >> 6] = ss; }
  __syncthreads();
  if (TID == 0) {
    float tot = sm[0] + sm[1] + sm[2] + sm[3];
    float tots = ssm[0] + ssm[1] + ssm[2] + ssm[3];
    float mean = tot * (1.f / 16384.f);
    float var = tots * (1.f / 16384.f) - mean * mean;
    stats[blk * 2] = mean;
    stats[blk * 2 + 1] = rsqrtf(var + 1e-5f);
  }
}

// ---------------- GroupNorm apply: -> xnT[b][l][c] bf16 ----------------
__global__ __launch_bounds__(256) void gn_apply(
    const float* __restrict__ x, const float* __restrict__ gamma,
    const float* __restrict__ beta, const float* __restrict__ stats,
    u16* __restrict__ xnT) {
  __shared__ u16 xt[32 * 520];
  int l0 = blockIdx.x * 32, b = blockIdx.y;
  int li = TID & 31, cb = TID >> 5;
#pragma unroll 4
  for (int it = 0; it < 64; ++it) {
    int c = it * 8 + cb;
    int g = c >> 4;
    float mean = stats[(b * 32 + g) * 2];
    float rstd = stats[(b * 32 + g) * 2 + 1];
    float ga = gamma[c] * rstd;
    float be = beta[c] - mean * ga;
    float v = x[((size_t)b * 512 + c) * 1024 + l0 + li];
    xt[li * 520 + c] = f2bf(v * ga + be);
  }
  __syncthreads();
  int li2 = TID >> 3, u0 = TID & 7;
#pragma unroll
  for (int it = 0; it < 8; ++it) {
    int unit = u0 + it * 8;
    u16x8 v = *(const u16x8*)&xt[li2 * 520 + unit * 8];
    *(u16x8*)&xnT[((size_t)b * 1024 + l0 + li2) * 512 + unit * 8] = v;
  }
}

// ---------------- unified QKV GEMM (transposed product D[l][o]) ----------------
__global__ __launch_bounds__(256) void qkv_gemm(
    const u16* __restrict__ A, const u16* __restrict__ Bt,
    const float* __restrict__ bias,
    u16* __restrict__ qT, u16* __restrict__ kT, u16* __restrict__ vbuf) {
  __shared__ u16 Al[8192], Bl[8192];
  int lin = blockIdx.x;            // 768 = 8 XCD chunks x 96 (12 m x 8 n)
  int b = lin & 7;                 // one batch per XCD
  int rem = lin >> 3;
  int mi = rem % 12, ni = rem / 12;
  int m0 = mi * 128, n0 = ni * 128;
  int lane = TID & 63, w = TID >> 6;
  int mw = (w >> 1) * 64, nw = (w & 1) * 64;
  const u16* Bb = Bt + (size_t)b * 1024 * 512;
  f32x4 acc[4][4] = {};
  for (int k0 = 0; k0 < 512; k0 += 64) {
#pragma unroll
    for (int u = 0; u < 4; ++u) {
      int unit = u * 256 + TID, row = unit >> 3, ch = unit & 7;
      gload16(&A[(size_t)(m0 + row) * 512 + k0 + swz(row, ch) * 8], &Al[unit * 8]);
      gload16(&Bb[(size_t)(n0 + row) * 512 + k0 + swz(row, ch) * 8], &Bl[unit * 8]);
    }
    __syncthreads();
    bf16x8 xf[4][2];
#pragma unroll
    for (int xi = 0; xi < 4; ++xi)
#pragma unroll
      for (int kf = 0; kf < 2; ++kf) {
        int row = nw + xi * 16 + (lane & 15);
        int lc = kf * 4 + (lane >> 4);
        xf[xi][kf] = ldfrag(&Bl[row * 64 + swz(row, lc) * 8]);
      }
#pragma unroll
    for (int yi = 0; yi < 4; ++yi) {
      int row = mw + yi * 16 + (lane & 15);
      int lc = lane >> 4;
      bf16x8 y0 = ldfrag(&Al[row * 64 + swz(row, lc) * 8]);
      bf16x8 y1 = ldfrag(&Al[row * 64 + swz(row, lc + 4) * 8]);
#pragma unroll
      for (int xi = 0; xi < 4; ++xi) {
        acc[xi][yi] = mfma16(xf[xi][0], y0, acc[xi][yi]);
        acc[xi][yi] = mfma16(xf[xi][1], y1, acc[xi][yi]);
      }
    }
    __syncthreads();
  }
  int sel = m0 >> 9;  // 0=Q 1=K 2=V
  int ho = w >> 1;
  u16* RP = ho ? Bl : Al;
  if (sel < 2) {
#pragma unroll
    for (int xi = 0; xi < 4; ++xi)
#pragma unroll
      for (int yi = 0; yi < 4; ++yi)
#pragma unroll
        for (int r = 0; r < 4; ++r) {
          int lloc = nw + xi * 16 + (lane >> 4) * 4 + r;
          int oc = yi * 16 + (lane & 15);
          float v = acc[xi][yi][r] + bias[m0 + ho * 64 + oc];
          if (sel == 0) v *= QSC;
          RP[lloc * 64 + swz(lloc, oc >> 3) * 8 + (oc & 7)] = f2bf(v);
        }
    __syncthreads();
    u16* dst = sel ? kT : qT;
    int h0 = (m0 & 511) >> 6;
#pragma unroll
    for (int uu = 0; uu < 4; ++uu) {
      int unit = uu * 256 + TID, row = unit >> 3, ch = unit & 7;
      u16x8 v0 = *(const u16x8*)&Al[row * 64 + swz(row, ch) * 8];
      u16x8 v1 = *(const u16x8*)&Bl[row * 64 + swz(row, ch) * 8];
      *(u16x8*)&dst[((size_t)(b * 8 + h0) * 1024 + n0 + row) * 64 + ch * 8] = v0;
      *(u16x8*)&dst[((size_t)(b * 8 + h0 + 1) * 1024 + n0 + row) * 64 + ch * 8] = v1;
    }
  } else {
#pragma unroll
    for (int xi = 0; xi < 4; ++xi)
#pragma unroll
      for (int yi = 0; yi < 4; ++yi)
#pragma unroll
        for (int r = 0; r < 4; ++r) {
          int lloc = nw + xi * 16 + (lane >> 4) * 4 + r;
          int oc = yi * 16 + (lane & 15);
          float v = acc[xi][yi][r] + bias[m0 + ho * 64 + oc];
          RP[oc * 128 + swz(oc, lloc >> 3) * 8 + (lloc & 7)] = f2bf(v);
        }
    __syncthreads();
    int h0 = (m0 - 1024) >> 6;
#pragma unroll
    for (int uu = 0; uu < 4; ++uu) {
      int unit = uu * 256 + TID, ro = unit >> 4, ch = unit & 15;
      u16x8 v0 = *(const u16x8*)&Al[ro * 128 + swz(ro, ch) * 8];
      u16x8 v1 = *(const u16x8*)&Bl[ro * 128 + swz(ro, ch) * 8];
      *(u16x8*)&vbuf[((size_t)(b * 8 + h0) * 64 + ro) * 1024 + n0 + ch * 8] = v0;
      *(u16x8*)&vbuf[((size_t)(b * 8 + h0 + 1) * 64 + ro) * 1024 + n0 + ch * 8] = v1;
    }
  }
}

// ---------------- MFMA flash attention, s-split, 512 threads ----------------
// Block = 128 q x (b,h); waves 0-3 process s in [0,512), waves 4-7 s in [512,1024)
// with private online-softmax state; flash-combine merge at the end via LDS.
// KVBLK=64 per group, double-buffered (2 x 32KB), ONE barrier per tile.
__global__ __launch_bounds__(512) void attn_mfma(const u16* __restrict__ qT,
                                                 const u16* __restrict__ kT,
                                                 const u16* __restrict__ vb,
                                                 u16* __restrict__ aT) {
  __shared__ u16 smem[32768];  // dbuf x [K g0|K g1|V g0|V g1] (4KB u16 each)
  int lin = blockIdx.x;
  int rem = lin >> 3;
  int bh = (lin & 7) * 8 + (rem >> 3);
  int t0 = (rem & 7) * 128;
  int b = bh >> 3, hd = bh & 7;
  int tid = TID;
  int lane = tid & 63, w = tid >> 6;   // w 0..7
  int grp = w >> 2, qw = w & 3;
  int h = lane >> 5, ln = lane & 31;
  int t = t0 + qw * 32 + ln;
  const u16* qp = qT + ((size_t)bh * 1024 + t) * 64;
  const u16* kbase = kT + (size_t)bh * 1024 * 64;
  const u16* vbase = vb + (size_t)bh * 64 * 1024;
  bf16x8 qf[4];
#pragma unroll
  for (int kc = 0; kc < 4; ++kc) qf[kc] = ldfrag(qp + kc * 16 + h * 8);
  float m_r = -1e30f, l_r = 0.f;
  f32x16 oacc[2] = {};

  auto STAGE = [&](int sn, u16* base) {
#pragma unroll
    for (int it = 0; it < 2; ++it) {  // K both groups: 1024 x 16B chunks
      int unit = it * 512 + tid;
      int g2 = unit >> 9, row = (unit >> 3) & 63, ch = unit & 7;
      gload16(&kbase[(size_t)(g2 * 512 + sn + row) * 64 + swz(row, ch) * 8],
              &base[unit * 8]);
    }
#pragma unroll
    for (int it = 0; it < 2; ++it) {  // V both groups
      int unit = it * 512 + tid;
      int g2 = unit >> 9, c = (unit >> 3) & 63, ch = unit & 7;
      gload16(&vbase[(size_t)c * 1024 + g2 * 512 + sn + swz(c, ch) * 8],
              &base[8192 + unit * 8]);
    }
  };

  STAGE(0, smem);
  __syncthreads();
  for (int tile = 0; tile < 8; ++tile) {
    u16* base = smem + (tile & 1) * 16384;
    const u16* Ks = base + grp * 4096;
    const u16* Vs = base + 8192 + grp * 4096;
    if (tile < 7) STAGE((tile + 1) * 64, smem + ((tile + 1) & 1) * 16384);
    // S^T[s][t] = sum_c K[s][c] * Q[t][c]  (log2 units; Q pre-scaled by QSC)
    f32x16 sacc[2] = {};
    __builtin_amdgcn_s_setprio(1);
#pragma unroll
    for (int sb = 0; sb < 2; ++sb) {
      int srow = sb * 32 + ln;
#pragma unroll
      for (int kc = 0; kc < 4; ++kc) {
        bf16x8 kf = ldfrag(&Ks[srow * 64 + swz(srow, kc * 2 + h) * 8]);
        sacc[sb] = mfma32(kf, qf[kc], sacc[sb]);
      }
    }
    __builtin_amdgcn_s_setprio(0);
    // online softmax; lane owns row t, 32 of 64 s-values (partner = lane^32)
    float mp[4];
#pragma unroll
    for (int q = 0; q < 4; ++q) {
      mp[q] = fmaxf(fmaxf(sacc[0][q * 4], sacc[0][q * 4 + 1]),
                    fmaxf(sacc[0][q * 4 + 2], sacc[0][q * 4 + 3]));
      mp[q] = fmaxf(mp[q], fmaxf(fmaxf(sacc[1][q * 4], sacc[1][q * 4 + 1]),
                                 fmaxf(sacc[1][q * 4 + 2], sacc[1][q * 4 + 3])));
    }
    float mx = xhalf_max(fmaxf(fmaxf(mp[0], mp[1]), fmaxf(mp[2], mp[3])));
    bool noresc = (__all(mx <= m_r + 8.f) != 0);
    if (!noresc) {
      float mn = fmaxf(m_r, mx);
      float al = fexp2(m_r - mn);
      m_r = mn;
      l_r *= al;
#pragma unroll
      for (int ca = 0; ca < 2; ++ca)
#pragma unroll
        for (int i = 0; i < 16; ++i) oacc[ca][i] *= al;
    }
    float rp[4] = {0.f, 0.f, 0.f, 0.f};
#pragma unroll
    for (int sb = 0; sb < 2; ++sb)
#pragma unroll
      for (int i = 0; i < 16; ++i) {
        float pv = fexp2(sacc[sb][i] - m_r);
        sacc[sb][i] = pv;
        rp[i & 3] += pv;
      }
    l_r += xhalf_add((rp[0] + rp[1]) + (rp[2] + rp[3]));
    // pack P pairs: W[sb][p4][e] = bf16x2 of s = 32sb + 8p4 + 4h + 2e (+1)
    unsigned W[2][4][2];
#pragma unroll
    for (int sb = 0; sb < 2; ++sb)
#pragma unroll
      for (int p4 = 0; p4 < 4; ++p4)
#pragma unroll
        for (int e = 0; e < 2; ++e)
          W[sb][p4][e] = cvtpk(sacc[sb][p4 * 4 + 2 * e], sacc[sb][p4 * 4 + 2 * e + 1]);
    // per 16-k step m: exchange with lane^32, assemble B-frag, PV
#pragma unroll
    for (int m = 0; m < 4; ++m) {
      int sb = m >> 1, q = (m & 1) * 2;
      unsigned a0 = W[sb][q][0], a1 = W[sb][q][1];
      unsigned b0 = W[sb][q + 1][0], b1 = W[sb][q + 1][1];
      unsigned s0w = h ? a0 : b0;
      unsigned s1w = h ? a1 : b1;
      unsigned x0 = (unsigned)__shfl_xor((int)s0w, 32);
      unsigned x1 = (unsigned)__shfl_xor((int)s1w, 32);
      unsigned w0 = h ? x0 : a0;
      unsigned w1 = h ? x1 : a1;
      unsigned w2 = h ? b0 : x0;
      unsigned w3 = h ? b1 : x1;
      uint4 pw = make_uint4(w0, w1, w2, w3);
      bf16x8 pf = __builtin_bit_cast(bf16x8, pw);
      __builtin_amdgcn_s_setprio(1);
#pragma unroll
      for (int ca = 0; ca < 2; ++ca) {
        int crow = ca * 32 + ln;
        bf16x8 vf = ldfrag(&Vs[crow * 64 + swz(crow, m * 2 + h) * 8]);
        oacc[ca] = mfma32(vf, pf, oacc[ca]);  // O^T[c][t]
      }
      __builtin_amdgcn_s_setprio(0);
    }
    __syncthreads();
  }
  // ---- flash combine of the two s-halves ----
  // LDS reuse: repack region bytes [0,16K); ml bytes [16K,20K); obuf bytes [32K,64K)
  float* mlb = (float*)(smem + 8192);
  float* obuf = (float*)(smem + 16384);
  int slot = qw * 64 + lane;
  mlb[(grp * 256 + slot) * 2 + 0] = m_r;
  mlb[(grp * 256 + slot) * 2 + 1] = l_r;
  __syncthreads();
  float m2 = mlb[((grp ^ 1) * 256 + slot) * 2 + 0];
  float l2 = mlb[((grp ^ 1) * 256 + slot) * 2 + 1];
  float mm = fmaxf(m_r, m2);
  float aown = fexp2(m_r - mm);
  float lm = l_r * aown + l2 * fexp2(m2 - mm);
#pragma unroll
  for (int ca = 0; ca < 2; ++ca)
#pragma unroll
    for (int i = 0; i < 16; ++i) oacc[ca][i] *= aown;
  if (grp == 1) {
#pragma unroll
    for (int ca = 0; ca < 2; ++ca)
#pragma unroll
      for (int i = 0; i < 16; ++i) obuf[(ca * 16 + i) * 256 + slot] = oacc[ca][i];
  }
  __syncthreads();
  if (grp == 0) {
#pragma unroll
    for (int ca = 0; ca < 2; ++ca)
#pragma unroll
      for (int i = 0; i < 16; ++i) oacc[ca][i] += obuf[(ca * 16 + i) * 256 + slot];
    // O^T -> LDS [t][c] (swizzled); repack region disjoint from obuf/ml
    float rl = 1.f / lm;
    int tloc = qw * 32 + ln;
#pragma unroll
    for (int ca = 0; ca < 2; ++ca)
#pragma unroll
      for (int p4 = 0; p4 < 4; ++p4)
#pragma unroll
        for (int e = 0; e < 2; ++e) {
          int r = p4 * 4 + e * 2;
          int c = ca * 32 + 8 * p4 + 4 * h + 2 * e;
          unsigned pk = cvtpk(oacc[ca][r] * rl, oacc[ca][r + 1] * rl);
          *(unsigned*)&smem[tloc * 64 + swz(tloc, c >> 3) * 8 + (c & 7)] = pk;
        }
  }
  __syncthreads();
#pragma unroll
  for (int u = 0; u < 2; ++u) {
    int unit = u * 512 + tid;
    int row = unit >> 3, ch = unit & 7;
    u16x8 v = *(const u16x8*)&smem[row * 64 + swz(row, ch) * 8];
    *(u16x8*)&aT[((size_t)b * 1024 + t0 + row) * 512 + hd * 64 + ch * 8] = v;
  }
}

// ---------------- proj GEMM: normal D[o][l], fp32 out + bias + resid ----------------
__global__ __launch_bounds__(256) void proj_gemm(
    const u16* __restrict__ A, const u16* __restrict__ Bt,
    const float* __restrict__ bias, const float* __restrict__ resid,
    float* __restrict__ of) {
  __shared__ u16 Al[8192], Bl[8192];
  int lin = blockIdx.x;           // 256 = 8 XCD chunks x 32 (4 m x 8 n)
  int b = lin & 7;
  int rem = lin >> 3;
  int mi = rem & 3, ni = rem >> 2;
  int m0 = mi * 128, n0 = ni * 128;
  int lane = TID & 63, w = TID >> 6;
  int mw = (w >> 1) * 64, nw = (w & 1) * 64;
  const u16* Bb = Bt + (size_t)b * 1024 * 512;
  f32x4 acc[4][4] = {};
  for (int k0 = 0; k0 < 512; k0 += 64) {
#pragma unroll
    for (int u = 0; u < 4; ++u) {
      int unit = u * 256 + TID, row = unit >> 3, ch = unit & 7;
      gload16(&A[(size_t)(m0 + row) * 512 + k0 + swz(row, ch) * 8], &Al[unit * 8]);
      gload16(&Bb[(size_t)(n0 + row) * 512 + k0 + swz(row, ch) * 8], &Bl[unit * 8]);
    }
    __syncthreads();
    bf16x8 xf[4][2];
#pragma unroll
    for (int xi = 0; xi < 4; ++xi)
#pragma unroll
      for (int kf = 0; kf < 2; ++kf) {
        int row = mw + xi * 16 + (lane & 15);
        int lc = kf * 4 + (lane >> 4);
        xf[xi][kf] = ldfrag(&Al[row * 64 + swz(row, lc) * 8]);
      }
#pragma unroll
    for (int yi = 0; yi < 4; ++yi) {
      int row = nw + yi * 16 + (lane & 15);
      int lc = lane >> 4;
      bf16x8 y0 = ldfrag(&Bl[row * 64 + swz(row, lc) * 8]);
      bf16x8 y1 = ldfrag(&Bl[row * 64 + swz(row, lc + 4) * 8]);
#pragma unroll
      for (int xi = 0; xi < 4; ++xi) {
        acc[xi][yi] = mfma16(xf[xi][0], y0, acc[xi][yi]);
        acc[xi][yi] = mfma16(xf[xi][1], y1, acc[xi][yi]);
      }
    }
    __syncthreads();
  }
#pragma unroll
  for (int xi = 0; xi < 4; ++xi)
#pragma unroll
    for (int yi = 0; yi < 4; ++yi)
#pragma unroll
      for (int r = 0; r < 4; ++r) {
        int o = m0 + mw + xi * 16 + (lane >> 4) * 4 + r;
        int l = n0 + nw + yi * 16 + (lane & 15);
        size_t idx = ((size_t)b * 512 + o) * 1024 + l;
        of[idx] = acc[xi][yi][r] + bias[o] + resid[idx];
      }
}

extern "C" void kernel_launch(void* const* d_in, const int* in_sizes, int n_in,
                              void* d_out, int out_size, void* d_ws, size_t ws_size,
                              hipStream_t stream) {
  const float* x = (const float*)d_in[0];
  const float* gamma = (const float*)d_in[1];
  const float* beta = (const float*)d_in[2];
  const float* w_qkv = (const float*)d_in[3];
  const float* b_qkv = (const float*)d_in[4];
  const float* w_proj = (const float*)d_in[5];
  const float* b_proj = (const float*)d_in[6];
  float* out = (float*)d_out;

  u16* qT = (u16*)d_ws;                    // 64bh*1024*64 = 4194304 u16 (8MB)
  u16* kT = qT + 4194304;                  // 8MB
  u16* vbuf = kT + 4194304;                // 8MB
  u16* aTb = vbuf + 4194304;               // 8MB
  u16* wqb = aTb + 4194304;                // 1.5MB
  u16* wpb = wqb + 786432;                 // 0.5MB
  float* stats = (float*)(wpb + 262144);   // 512 floats
  u16* xnT = (u16*)d_out;                  // 8MB scratch in d_out (overwritten by proj)

  prep_stats<<<dim3(1280), dim3(256), 0, stream>>>(w_qkv, w_proj, wqb, wpb, x, stats);
  gn_apply<<<dim3(32, 8), dim3(256), 0, stream>>>(x, gamma, beta, stats, xnT);
  qkv_gemm<<<dim3(768), dim3(256), 0, stream>>>(wqb, xnT, b_qkv, qT, kT, vbuf);
  attn_mfma<<<dim3(512), dim3(512), 0, stream>>>(qT, kT, vbuf, aTb);
  proj_gemm<<<dim3(256), dim3(256), 0, stream>>>(wpb, aTb, b_proj, x, out);
}